// Round 8
// baseline (8050.353 us; speedup 1.0000x reference)
//
#include <hip/hip_runtime.h>
#include <stdint.h>

typedef unsigned short u16;
typedef short v8s __attribute__((ext_vector_type(8)));
typedef float v4f __attribute__((ext_vector_type(4)));

#define B_ 64
#define S_ 1024
#define IN_ 256
#define H_ 512
#define OUT_ 256
#define BS_ (B_ * S_)                 // 65536
#define GS_ ((size_t)BS_ * H_)        // elems per gate buffer
#define HP_ (H_ + 8)                  // padded LDS row, L0 (u16)
#define KP1_ (1024 + 8)               // padded LDS row, L1 stacked-K (u16)
#define FPAD_ 16                      // flag padding: 16 u32 = 64 B/line
#define TMASK_ 0x0000FFFF0000FFFFull  // tag bits of a packed u64

static __device__ __forceinline__ u16 f2bf(float f) {
  uint32_t u = __float_as_uint(f);
  u += 0x7FFFu + ((u >> 16) & 1u);   // round-to-nearest-even
  return (u16)(u >> 16);
}
static __device__ __forceinline__ float bf2f(u16 h) {
  return __uint_as_float(((uint32_t)h) << 16);
}
static __device__ __forceinline__ v4f mfma16(v8s a, v8s b, v4f c) {
  return __builtin_amdgcn_mfma_f32_16x16x32_bf16(a, b, c, 0, 0, 0);
}
// Relaxed agent-scope accesses: served at the coherence point (r3/r6-proven).
static __device__ __forceinline__ uint64_t cload64(const uint64_t* p) {
  return __hip_atomic_load(p, __ATOMIC_RELAXED, __HIP_MEMORY_SCOPE_AGENT);
}
static __device__ __forceinline__ void cstore64(uint64_t* p, uint64_t v) {
  __hip_atomic_store(p, v, __ATOMIC_RELAXED, __HIP_MEMORY_SCOPE_AGENT);
}
static __device__ __forceinline__ void cstore32(uint32_t* p, uint32_t v) {
  __hip_atomic_store(p, v, __ATOMIC_RELAXED, __HIP_MEMORY_SCOPE_AGENT);
}
static __device__ __forceinline__ void pollge(const uint32_t* p, uint32_t want) {
  while (__hip_atomic_load(p, __ATOMIC_RELAXED, __HIP_MEMORY_SCOPE_AGENT) < want)
    __builtin_amdgcn_s_sleep(1);
}
static __device__ __forceinline__ uint64_t tagpat(uint32_t tag) {
  return (uint64_t)tag * 0x0000000100000001ull;
}
static __device__ __forceinline__ void polltag(const uint64_t* p, uint64_t pat) {
  while ((cload64(p) ^ pat) & TMASK_) __builtin_amdgcn_s_sleep(1);
}
// store 2 adjacent tagged cols (executed by even-fr lanes; shfl by all)
static __device__ __forceinline__ void store_pair(uint32_t* blk, int row,
                                                  int gcol, float v, int fr,
                                                  uint32_t tag) {
  float o1 = __shfl_xor(v, 1);
  if ((fr & 1) == 0) {
    uint64_t qv = (uint64_t)(((uint32_t)f2bf(v) << 16) | tag) |
                  ((uint64_t)(((uint32_t)f2bf(o1) << 16) | tag) << 32);
    cstore64((uint64_t*)(blk + (size_t)row * 512 + gcol), qv);
  }
}
// stage one (or two) tagged 16x512-u32 blocks into LDS (strip tags).
// rs = LDS row stride in u16 units. Per-word validation catches store skew.
static __device__ __forceinline__ void stage2(const uint64_t* a64, uint64_t pa,
                                              u16* la, const uint64_t* b64,
                                              uint64_t pb, u16* lb, int rs,
                                              int tid) {
  uint64_t qa[16], qb[16];
#pragma unroll
  for (int i = 0; i < 16; ++i) qa[i] = cload64(a64 + i * 256 + tid);
  if (b64) {
#pragma unroll
    for (int i = 0; i < 16; ++i) qb[i] = cload64(b64 + i * 256 + tid);
  }
#pragma unroll
  for (int i = 0; i < 16; ++i) {
    while ((qa[i] ^ pa) & TMASK_) {
      __builtin_amdgcn_s_sleep(1);
      qa[i] = cload64(a64 + i * 256 + tid);
    }
    int d = i * 256 + tid;
    *(uint32_t*)(la + (size_t)(d >> 8) * rs + (d & 255) * 2) =
        ((uint32_t)(qa[i] >> 16) & 0xFFFFu) |
        ((uint32_t)(qa[i] >> 32) & 0xFFFF0000u);
  }
  if (b64) {
#pragma unroll
    for (int i = 0; i < 16; ++i) {
      while ((qb[i] ^ pb) & TMASK_) {
        __builtin_amdgcn_s_sleep(1);
        qb[i] = cload64(b64 + i * 256 + tid);
      }
      int d = i * 256 + tid;
      *(uint32_t*)(lb + (size_t)(d >> 8) * rs + (d & 255) * 2) =
          ((uint32_t)(qb[i] >> 16) & 0xFFFFu) |
          ((uint32_t)(qb[i] >> 32) & 0xFFFF0000u);
    }
  }
}

// ---------------------------------------------------------------- utilities
__global__ void cast_input_kernel(const float* __restrict__ src,
                                  u16* __restrict__ dst, int n4) {
  int i = blockIdx.x * blockDim.x + threadIdx.x;
  int stride = gridDim.x * blockDim.x;
  for (; i < n4; i += stride) {
    float4 v = ((const float4*)src)[i];
    uint32_t lo = (uint32_t)f2bf(v.x) | ((uint32_t)f2bf(v.y) << 16);
    uint32_t hi = (uint32_t)f2bf(v.z) | ((uint32_t)f2bf(v.w) << 16);
    ((uint2*)dst)[i] = make_uint2(lo, hi);
  }
}

// dst[n*dstK + k0 + k] = bf16(src[k*N + n])
__global__ void pack_transpose_k(const float* __restrict__ src,
                                 u16* __restrict__ dst, int K, int N,
                                 int dstK, int k0) {
  int i = blockIdx.x * blockDim.x + threadIdx.x;
  int total = K * N;
  int stride = gridDim.x * blockDim.x;
  for (; i < total; i += stride) {
    int n = i / K, k = i - n * K;
    dst[(size_t)n * dstK + k0 + k] = f2bf(src[(size_t)k * N + n]);
  }
}

// ---------------------------------------------------------------- GEMM
__global__ void __launch_bounds__(256) gemm_kernel(
    const u16* __restrict__ A, const u16* __restrict__ Bt, int N, int K,
    u16* __restrict__ outb, float* __restrict__ outf,
    const float* __restrict__ bias, int mode) {
  const int bn = blockIdx.x * 64;
  const int bm = blockIdx.y * 64;
  const int w = threadIdx.x >> 6;
  const int lane = threadIdx.x & 63;
  const int wm = (w >> 1) * 32, wn = (w & 1) * 32;
  const int fr = lane & 15;
  const int kb = (lane >> 4) * 8;
  v4f acc00 = {0,0,0,0}, acc01 = {0,0,0,0}, acc10 = {0,0,0,0}, acc11 = {0,0,0,0};
  const u16* a0p = A + (size_t)(bm + wm + fr) * K + kb;
  const u16* a1p = a0p + (size_t)16 * K;
  const u16* b0p = Bt + (size_t)(bn + wn + fr) * K + kb;
  const u16* b1p = b0p + (size_t)16 * K;
  for (int kk = 0; kk < K; kk += 32) {
    v8s a0 = *(const v8s*)(a0p + kk);
    v8s a1 = *(const v8s*)(a1p + kk);
    v8s b0 = *(const v8s*)(b0p + kk);
    v8s b1 = *(const v8s*)(b1p + kk);
    acc00 = mfma16(a0, b0, acc00);
    acc01 = mfma16(a0, b1, acc01);
    acc10 = mfma16(a1, b0, acc10);
    acc11 = mfma16(a1, b1, acc11);
  }
  v4f accs[2][2] = {{acc00, acc01}, {acc10, acc11}};
  const int rb = (lane >> 4) * 4;
#pragma unroll
  for (int mi = 0; mi < 2; ++mi)
#pragma unroll
    for (int ni = 0; ni < 2; ++ni)
#pragma unroll
      for (int j = 0; j < 4; ++j) {
        int row = bm + wm + mi * 16 + rb + j;
        int col = bn + wn + ni * 16 + fr;
        float v = accs[mi][ni][j];
        if (mode == 0) {
          int gate = col >> 9, c = col & (H_ - 1);
          outb[(size_t)gate * GS_ + (size_t)row * H_ + c] = f2bf(v);
        } else {
          outf[(size_t)row * N + col] = v + bias[col];
        }
      }
}

// ---------------------------------------------------------------- pipelined
// two-layer GRU scan, canary-tagged exchange (no drains, no flag barriers).
// Exchange word = (bf16<<16)|tag, tag = t+1 (monotone per launch; buffers
// zeroed each launch). Consumers gate bulk loads behind 16/32-lane canary
// polls (one data word per producer), then per-word tag validation.
// 192 WGs: bid<64 = L0 (4grp x 16slab x 32col); bid>=64 = L1 (4grp x 32slab
// x 16col, stacked-K [h0(t); h1(t-1)] @ [Win;Wh]).
__global__ void __launch_bounds__(256, 1) gru_pipe_kernel(
    const u16* xproj,                // [3][BS_][H_] bf16 (layer-0 z,r,g)
    const u16* __restrict__ Wht0,    // [3][H_][H_]  layer-0 recurrent^T
    const u16* __restrict__ Wstk1,   // [3][H_][1024] layer-1 stacked
    const float* __restrict__ bz0, const float* __restrict__ br0,
    const float* __restrict__ bg0,
    const float* __restrict__ bz1, const float* __restrict__ br1,
    const float* __restrict__ bg1,
    const float* __restrict__ hs,    // [B_][2][H_] f32 initial state
    uint32_t* h0x,                   // [2][4][16][512] tagged h0 (parity)
    uint32_t* hr0x,                  // [4][16][512] tagged hr0
    uint32_t* h1x,                   // [4][16][512] tagged h1
    uint32_t* hr1x,                  // [4][16][512] tagged hr1
    u16* seqout,                     // [B_][S_][H_] layer-1 output (alias z)
    float* __restrict__ hfinal,      // [2*B_][H_] f32 (d_out tail)
    uint32_t* c1g) {                 // [4][32][FPAD_] backpressure flags
  __shared__ __align__(16) char pool[134144];
  const int tid = threadIdx.x;
  const int bid = blockIdx.x;
  const int w = tid >> 6, lane = tid & 63;
  const int fr = lane & 15;
  const int kb = (lane >> 4) * 8;
  const int rb = (lane >> 4) * 4;

  if (bid < 64) {
    // ================= LAYER 0 =================
    u16* ldsW = (u16*)pool;                            // [3][32][HP_]
    u16 (*ldsX)[HP_] = (u16(*)[HP_])(pool + 99840);    // [16][HP_]
    float (*h32)[32] = (float(*)[32])(pool + 116480);  // [16][32]
    const int grp = bid & 3;
    const int slab = bid >> 2;
    const int j0 = slab * 32;
    const int gb = grp * 16;

    for (int idx = tid; idx < 3 * 32 * 64; idx += 256) {
      int gate = idx >> 11;
      int rem = idx & 2047;
      int cl = rem >> 6;
      int kc = (rem & 63) * 8;
      *(v8s*)&ldsW[((gate * 32) + cl) * HP_ + kc] =
          *(const v8s*)(Wht0 + ((size_t)gate * H_ + (j0 + cl)) * H_ + kc);
    }
    for (int i = tid; i < 16 * H_; i += 256) {
      int row = i >> 9, col = i & (H_ - 1);
      ldsX[row][col] = f2bf(hs[((size_t)(gb + row) * 2 + 0) * H_ + col]);
    }
    for (int i = tid; i < 16 * 32; i += 256) {
      int row = i >> 5, cl = i & 31;
      h32[row][cl] = hs[((size_t)(gb + row) * 2 + 0) * H_ + j0 + cl];
    }
    __syncthreads();

    const int nt = w & 1;
    const int gateA = w >> 1;          // waves 0,1 -> z ; waves 2,3 -> r
    const int colL = nt * 16 + fr;
    const int gcol = j0 + colL;
    const float biasA = (gateA == 0) ? bz0[gcol] : br0[gcol];
    const float biasG = bg0[gcol];
    uint32_t* hr0b = hr0x + (size_t)grp * 8192;
    uint32_t* c1gg = c1g + (size_t)grp * 32 * FPAD_;
    const u16* xA = xproj + (size_t)gateA * GS_;
    const u16* xG = xproj + (size_t)2 * GS_;
    const u16* wA = ldsW + ((size_t)(gateA * 32) + colL) * HP_;
    const u16* wG = ldsW + ((size_t)(2 * 32) + colL) * HP_;

    float zv[4] = {0.f, 0.f, 0.f, 0.f};

    for (int t = 0; t < S_; ++t) {
      if (t > 0) {
        const uint64_t* b64 =
            (const uint64_t*)(h0x + (size_t)(((t - 1) & 1) * 4 + grp) * 8192);
        if (t >= 2 && tid < 32) pollge(c1gg + tid * FPAD_, (uint32_t)(t - 1));
        if (tid < 16) polltag(b64 + 3840 + 16 * tid, tagpat((uint32_t)t));
        __syncthreads();
        stage2(b64, tagpat((uint32_t)t), &ldsX[0][0], nullptr, 0, nullptr,
               HP_, tid);
        __syncthreads();
      }

      // ---- phase A: z (waves 0,1; also hoist xg), r -> hr (waves 2,3) ----
      float xpre[4], xpg[4];
      if (w < 2) {
#pragma unroll
        for (int j = 0; j < 4; ++j) {
          xpre[j] = bf2f(xA[((size_t)(gb + rb + j) * S_ + t) * H_ + gcol]);
          xpg[j] = bf2f(xG[((size_t)(gb + rb + j) * S_ + t) * H_ + gcol]);
        }
      } else {
#pragma unroll
        for (int j = 0; j < 4; ++j)
          xpre[j] = bf2f(xA[((size_t)(gb + rb + j) * S_ + t) * H_ + gcol]);
      }
      v4f acc0 = {0,0,0,0}, acc1 = {0,0,0,0};
#pragma unroll
      for (int kk = 0; kk < 8; ++kk) {
        acc0 = mfma16(*(const v8s*)&ldsX[fr][kk * 32 + kb],
                      *(const v8s*)(wA + kk * 32 + kb), acc0);
        acc1 = mfma16(*(const v8s*)&ldsX[fr][256 + kk * 32 + kb],
                      *(const v8s*)(wA + 256 + kk * 32 + kb), acc1);
      }
      float pre[4];
#pragma unroll
      for (int j = 0; j < 4; ++j) {
        float s = acc0[j] + acc1[j] + xpre[j] + biasA;
        pre[j] = 1.0f / (1.0f + __expf(-s));
      }
      if (gateA == 0) {
#pragma unroll
        for (int j = 0; j < 4; ++j) zv[j] = pre[j];
      } else {
#pragma unroll
        for (int j = 0; j < 4; ++j) {
          float v = pre[j] * h32[rb + j][colL];
          store_pair(hr0b, rb + j, gcol, v, fr, (uint32_t)(t + 1));
        }
      }
      // hr exchange: canary poll -> barrier -> bulk stage
      if (tid < 16)
        polltag((const uint64_t*)hr0b + 3840 + 16 * tid,
                tagpat((uint32_t)(t + 1)));
      __syncthreads();   // also: all ldsX(h) MFMA reads complete
      stage2((const uint64_t*)hr0b, tagpat((uint32_t)(t + 1)), &ldsX[0][0],
             nullptr, 0, nullptr, HP_, tid);
      __syncthreads();

      // ---- phase B: g (waves 0,1), h update + tagged broadcast ----
      if (w < 2) {
        v4f g0 = {0,0,0,0}, g1 = {0,0,0,0};
#pragma unroll
        for (int kk = 0; kk < 8; ++kk) {
          g0 = mfma16(*(const v8s*)&ldsX[fr][kk * 32 + kb],
                      *(const v8s*)(wG + kk * 32 + kb), g0);
          g1 = mfma16(*(const v8s*)&ldsX[fr][256 + kk * 32 + kb],
                      *(const v8s*)(wG + 256 + kk * 32 + kb), g1);
        }
        uint32_t* h0slot = h0x + (size_t)((t & 1) * 4 + grp) * 8192;
#pragma unroll
        for (int j = 0; j < 4; ++j) {
          int b = gb + rb + j;
          float gval = tanhf(g0[j] + g1[j] + xpg[j] + biasG);
          float hold = h32[rb + j][colL];
          float hnew = zv[j] * hold + (1.0f - zv[j]) * gval;
          h32[rb + j][colL] = hnew;
          store_pair(h0slot, rb + j, gcol, hnew, fr, (uint32_t)(t + 1));
          if (t == S_ - 1) hfinal[(size_t)b * H_ + gcol] = hnew;
        }
      }
      // no trailing barrier: next-iteration poll+sync guards ldsX overwrite
    }
  } else {
    // ================= LAYER 1 =================
    u16* ldsW = (u16*)pool;                              // [3][16][KP1_]
    u16 (*ldsX)[KP1_] = (u16(*)[KP1_])(pool + 99072);    // [16][KP1_]
    float (*h32b)[16] = (float(*)[16])(pool + 132096);   // [16][16]
    float (*xg32)[16] = (float(*)[16])(pool + 133120);   // [16][16]
    const int b2 = bid - 64;
    const int grp = b2 & 3;
    const int slab = b2 >> 2;          // 0..31
    const int j0 = slab * 16;
    const int gb = grp * 16;
    const int gcol = j0 + fr;

    for (int idx = tid; idx < 3 * 16 * 128; idx += 256) {
      int gate = idx >> 11;
      int rem = idx & 2047;
      int cl = rem >> 7;
      int kc = (rem & 127) * 8;
      *(v8s*)&ldsW[((gate * 16) + cl) * KP1_ + kc] =
          *(const v8s*)(Wstk1 + ((size_t)(gate * H_) + (j0 + cl)) * 1024 + kc);
    }
    for (int i = tid; i < 16 * H_; i += 256) {
      int row = i >> 9, col = i & (H_ - 1);
      ldsX[row][512 + col] = f2bf(hs[((size_t)(gb + row) * 2 + 1) * H_ + col]);
    }
    for (int i = tid; i < 16 * 16; i += 256) {
      int row = i >> 4, c = i & 15;
      h32b[row][c] = hs[((size_t)(gb + row) * 2 + 1) * H_ + j0 + c];
    }
    __syncthreads();

    const float bzv = bz1[gcol], brv = br1[gcol], bgv = bg1[gcol];
    uint32_t* h1b = h1x + (size_t)grp * 8192;
    uint32_t* hr1b = hr1x + (size_t)grp * 8192;
    uint32_t* c1gg = c1g + (size_t)grp * 32 * FPAD_;
    const u16* wZ = ldsW + ((size_t)(0 * 16) + fr) * KP1_;
    const u16* wR = ldsW + ((size_t)(1 * 16) + fr) * KP1_;
    const u16* wG = ldsW + ((size_t)(2 * 16) + fr) * KP1_;
    float* hf1 = hfinal + (size_t)B_ * H_;

    float zv[4] = {0.f, 0.f, 0.f, 0.f};

    for (int t = 0; t < S_; ++t) {
      // stage h0(t) (slot t&1, tag t+1) and h1(t-1) (tag t)
      const uint64_t* b064 =
          (const uint64_t*)(h0x + (size_t)((t & 1) * 4 + grp) * 8192);
      if (tid < 16) polltag(b064 + 3840 + 16 * tid, tagpat((uint32_t)(t + 1)));
      else if (t > 0 && tid < 48)
        polltag((const uint64_t*)h1b + 3840 + 8 * (tid - 16),
                tagpat((uint32_t)t));
      __syncthreads();
      stage2(b064, tagpat((uint32_t)(t + 1)), &ldsX[0][0],
             (t > 0) ? (const uint64_t*)h1b : nullptr, tagpat((uint32_t)t),
             &ldsX[0][512], KP1_, tid);
      __syncthreads();
      if (tid == 0) cstore32(&c1gg[slab * FPAD_], (uint32_t)(t + 1));

      // ---- phase A: w0 z (K=1024), w1 r (K=1024)->hr, w2 xg (K=512) ----
      if (w < 2) {
        const u16* wB = (w == 0) ? wZ : wR;
        v4f a0 = {0,0,0,0}, a1 = {0,0,0,0}, a2 = {0,0,0,0}, a3 = {0,0,0,0};
#pragma unroll
        for (int kk = 0; kk < 8; ++kk) {
          a0 = mfma16(*(const v8s*)&ldsX[fr][kk * 32 + kb],
                      *(const v8s*)(wB + kk * 32 + kb), a0);
          a1 = mfma16(*(const v8s*)&ldsX[fr][256 + kk * 32 + kb],
                      *(const v8s*)(wB + 256 + kk * 32 + kb), a1);
          a2 = mfma16(*(const v8s*)&ldsX[fr][512 + kk * 32 + kb],
                      *(const v8s*)(wB + 512 + kk * 32 + kb), a2);
          a3 = mfma16(*(const v8s*)&ldsX[fr][768 + kk * 32 + kb],
                      *(const v8s*)(wB + 768 + kk * 32 + kb), a3);
        }
        float pre[4];
#pragma unroll
        for (int j = 0; j < 4; ++j) {
          float s = a0[j] + a1[j] + a2[j] + a3[j] + ((w == 0) ? bzv : brv);
          pre[j] = 1.0f / (1.0f + __expf(-s));
        }
        if (w == 0) {
#pragma unroll
          for (int j = 0; j < 4; ++j) zv[j] = pre[j];
        } else {
#pragma unroll
          for (int j = 0; j < 4; ++j) {
            float v = pre[j] * h32b[rb + j][fr];
            store_pair(hr1b, rb + j, gcol, v, fr, (uint32_t)(t + 1));
          }
        }
      } else if (w == 2) {
        v4f a0 = {0,0,0,0}, a1 = {0,0,0,0};
#pragma unroll
        for (int kk = 0; kk < 8; ++kk) {
          a0 = mfma16(*(const v8s*)&ldsX[fr][kk * 32 + kb],
                      *(const v8s*)(wG + kk * 32 + kb), a0);
          a1 = mfma16(*(const v8s*)&ldsX[fr][256 + kk * 32 + kb],
                      *(const v8s*)(wG + 256 + kk * 32 + kb), a1);
        }
#pragma unroll
        for (int j = 0; j < 4; ++j) xg32[rb + j][fr] = a0[j] + a1[j];
      }
      // hr1 exchange: canary poll -> barrier -> bulk stage into 2nd half
      if (tid < 32)
        polltag((const uint64_t*)hr1b + 3840 + 8 * tid,
                tagpat((uint32_t)(t + 1)));
      __syncthreads();
      stage2((const uint64_t*)hr1b, tagpat((uint32_t)(t + 1)), &ldsX[0][512],
             nullptr, 0, nullptr, KP1_, tid);
      __syncthreads();

      // ---- phase B: w0 g (hr half) + update + broadcast + seq ----
      if (w == 0) {
        v4f g0 = {0,0,0,0}, g1 = {0,0,0,0};
#pragma unroll
        for (int kk = 0; kk < 8; ++kk) {
          g0 = mfma16(*(const v8s*)&ldsX[fr][512 + kk * 32 + kb],
                      *(const v8s*)(wG + 512 + kk * 32 + kb), g0);
          g1 = mfma16(*(const v8s*)&ldsX[fr][768 + kk * 32 + kb],
                      *(const v8s*)(wG + 768 + kk * 32 + kb), g1);
        }
#pragma unroll
        for (int j = 0; j < 4; ++j) {
          int b = gb + rb + j;
          float gval = tanhf(g0[j] + g1[j] + xg32[rb + j][fr] + bgv);
          float hold = h32b[rb + j][fr];
          float hnew = zv[j] * hold + (1.0f - zv[j]) * gval;
          h32b[rb + j][fr] = hnew;
          store_pair(h1b, rb + j, gcol, hnew, fr, (uint32_t)(t + 1));
          uint32_t c0 = f2bf(hnew);
          float o1 = __shfl_xor(hnew, 1);
          uint32_t c1 = f2bf(o1);
          uint32_t pk = (fr & 1) ? (c1 | (c0 << 16)) : (c0 | (c1 << 16));
          uint32_t pk2 = __shfl_xor(pk, 2);
          if ((fr & 3) == 0) {
            uint64_t qv = (uint64_t)pk | ((uint64_t)pk2 << 32);
            *(uint64_t*)&seqout[((size_t)b * S_ + t) * H_ + gcol] = qv;
          }
          if (t == S_ - 1) hf1[(size_t)b * H_ + gcol] = hnew;
        }
      }
      // no trailing barrier: next-iteration poll+sync guards ldsX overwrite
    }
  }
}

// ---------------------------------------------------------------- launch
extern "C" void kernel_launch(void* const* d_in, const int* in_sizes, int n_in,
                              void* d_out, int out_size, void* d_ws,
                              size_t ws_size, hipStream_t stream) {
  const float* input = (const float*)d_in[0];
  const float* hs = (const float*)d_in[1];
  const float* W_in[2][3] = {
      {(const float*)d_in[2], (const float*)d_in[5], (const float*)d_in[8]},
      {(const float*)d_in[11], (const float*)d_in[14], (const float*)d_in[17]}};
  const float* W_h[2][3] = {
      {(const float*)d_in[3], (const float*)d_in[6], (const float*)d_in[9]},
      {(const float*)d_in[12], (const float*)d_in[15], (const float*)d_in[18]}};
  const float* bias[2][3] = {
      {(const float*)d_in[4], (const float*)d_in[7], (const float*)d_in[10]},
      {(const float*)d_in[13], (const float*)d_in[16], (const float*)d_in[19]}};
  const float* Wo = (const float*)d_in[20];
  const float* bo = (const float*)d_in[21];
  float* out = (float*)d_out;

  // ---------------- workspace layout (peak ~207.8 MB) ----------------
  char* ws = (char*)d_ws;
  u16* xproj   = (u16*)(ws + 0);             // 201,326,592 B
  u16* wtin0   = (u16*)(ws + 201326592);     // [1536][256]   786,432 B
  u16* wth0    = (u16*)(ws + 202113024);     // [3][512][512] 1,572,864 B
  u16* wstk1   = (u16*)(ws + 203685888);     // [3][512][1024] 3,145,728 B
  u16* wot     = (u16*)(ws + 206831616);     // [256][512]    262,144 B
  uint32_t* h0x  = (uint32_t*)(ws + 207093760); // [2][4][16][512] 262,144 B
  uint32_t* hr0x = (uint32_t*)(ws + 207355904); // [4][16][512]    131,072 B
  uint32_t* h1x  = (uint32_t*)(ws + 207486976); // [4][16][512]    131,072 B
  uint32_t* hr1x = (uint32_t*)(ws + 207618048); // [4][16][512]    131,072 B
  uint32_t* c1g  = (uint32_t*)(ws + 207749120); // [4][32][FPAD_]    8,192 B

  u16* inbf = (u16*)d_out;                   // 33.5 MB in d_out y-region
  u16* seq2 = xproj;                         // layer-1 seq aliases z-slice

  // 1. cast input to bf16 (into d_out y-region scratch)
  cast_input_kernel<<<2048, 256, 0, stream>>>(input, inbf, BS_ * IN_ / 4);

  // 2. pack weights: L0 separate, L1 stacked [Win; Wh] (K=1024)
  for (int g = 0; g < 3; ++g) {
    pack_transpose_k<<<256, 256, 0, stream>>>(
        W_in[0][g], wtin0 + (size_t)g * H_ * IN_, IN_, H_, IN_, 0);
    pack_transpose_k<<<256, 256, 0, stream>>>(
        W_h[0][g], wth0 + (size_t)g * H_ * H_, H_, H_, H_, 0);
    pack_transpose_k<<<256, 256, 0, stream>>>(
        W_in[1][g], wstk1 + (size_t)g * H_ * 1024, H_, H_, 1024, 0);
    pack_transpose_k<<<256, 256, 0, stream>>>(
        W_h[1][g], wstk1 + (size_t)g * H_ * 1024, H_, H_, 1024, 512);
  }
  pack_transpose_k<<<256, 256, 0, stream>>>(Wo, wot, H_, OUT_, H_, 0);

  // 3. layer-0 input projections for all timesteps: [BS] x [1536]
  gemm_kernel<<<dim3(24, 1024), 256, 0, stream>>>(
      inbf, wtin0, 1536, IN_, xproj, nullptr, nullptr, 0);

  // 4. zero ALL tagged exchange buffers + flags (replay safety: tags repeat
  //    across graph replays), then run the pipelined scan
  hipMemsetAsync(h0x, 0, 663552, stream);
  const size_t ysz = (size_t)BS_ * OUT_;
  float* hfin = out + ysz;
  gru_pipe_kernel<<<dim3(192), dim3(256), 0, stream>>>(
      xproj, wth0, wstk1, bias[0][0], bias[0][1], bias[0][2], bias[1][0],
      bias[1][1], bias[1][2], hs, h0x, hr0x, h1x, hr1x, seq2, hfin, c1g);

  // 5. output projection: y = seq2 @ Wo + bo (overwrites inbf, dead by now)
  gemm_kernel<<<dim3(4, 1024), 256, 0, stream>>>(seq2, wot, OUT_, H_, nullptr,
                                                 out, bo, 1);
}

// Round 9
// 6685.522 us; speedup vs baseline: 1.2041x; 1.2041x over previous
//
#include <hip/hip_runtime.h>
#include <stdint.h>

typedef unsigned short u16;
typedef short v8s __attribute__((ext_vector_type(8)));
typedef float v4f __attribute__((ext_vector_type(4)));

#define B_ 64
#define S_ 1024
#define IN_ 256
#define H_ 512
#define OUT_ 256
#define BS_ (B_ * S_)                 // 65536
#define GS_ ((size_t)BS_ * H_)        // elems per gate buffer
#define HP_ (H_ + 8)                  // padded LDS row, L0 (u16)
#define KP1_ (1024 + 8)               // padded LDS row, L1 stacked-K (u16)
#define FPAD_ 16                      // flag padding: 16 u32 = 64 B/line

static __device__ __forceinline__ u16 f2bf(float f) {
  uint32_t u = __float_as_uint(f);
  u += 0x7FFFu + ((u >> 16) & 1u);   // round-to-nearest-even
  return (u16)(u >> 16);
}
static __device__ __forceinline__ float bf2f(u16 h) {
  return __uint_as_float(((uint32_t)h) << 16);
}
static __device__ __forceinline__ v4f mfma16(v8s a, v8s b, v4f c) {
  return __builtin_amdgcn_mfma_f32_16x16x32_bf16(a, b, c, 0, 0, 0);
}
// Relaxed agent-scope accesses: served at the coherence point (r3/r6-proven).
static __device__ __forceinline__ uint64_t cload64(const uint64_t* p) {
  return __hip_atomic_load(p, __ATOMIC_RELAXED, __HIP_MEMORY_SCOPE_AGENT);
}
static __device__ __forceinline__ void cstore64(uint64_t* p, uint64_t v) {
  __hip_atomic_store(p, v, __ATOMIC_RELAXED, __HIP_MEMORY_SCOPE_AGENT);
}
static __device__ __forceinline__ void cstore32(uint32_t* p, uint32_t v) {
  __hip_atomic_store(p, v, __ATOMIC_RELAXED, __HIP_MEMORY_SCOPE_AGENT);
}
static __device__ __forceinline__ uint32_t cload32(const uint32_t* p) {
  return __hip_atomic_load(p, __ATOMIC_RELAXED, __HIP_MEMORY_SCOPE_AGENT);
}
// Mid-step de-contended group barrier (r6/r7-proven). Caller must have
// drained exchange stores (vmcnt(0)) on every storing wave.
template <int NS>
static __device__ __forceinline__ void slab_barrier(uint32_t* flagbase,
                                                    int slab, uint32_t want,
                                                    int tid) {
  __syncthreads();
  if (tid == 0)
    __hip_atomic_store(flagbase + slab * FPAD_, want, __ATOMIC_RELAXED,
                       __HIP_MEMORY_SCOPE_AGENT);
  if (tid < NS) {
    while (cload32(flagbase + tid * FPAD_) < want) __builtin_amdgcn_s_sleep(1);
  }
  __syncthreads();
}
// pack own col value + 3 neighbors into a u64 of 4 bf16 (lanes fr&3==0 store)
static __device__ __forceinline__ void pack_store4(u16* dst, float v, int fr) {
  float o1 = __shfl_xor(v, 1);
  uint32_t c0 = f2bf(v), c1 = f2bf(o1);
  uint32_t pk = (fr & 1) ? (c1 | (c0 << 16)) : (c0 | (c1 << 16));
  uint32_t pk2 = __shfl_xor(pk, 2);
  if ((fr & 3) == 0)
    cstore64((uint64_t*)dst, (uint64_t)pk | ((uint64_t)pk2 << 32));
}

// ---------------------------------------------------------------- utilities
__global__ void cast_input_kernel(const float* __restrict__ src,
                                  u16* __restrict__ dst, int n4) {
  int i = blockIdx.x * blockDim.x + threadIdx.x;
  int stride = gridDim.x * blockDim.x;
  for (; i < n4; i += stride) {
    float4 v = ((const float4*)src)[i];
    uint32_t lo = (uint32_t)f2bf(v.x) | ((uint32_t)f2bf(v.y) << 16);
    uint32_t hi = (uint32_t)f2bf(v.z) | ((uint32_t)f2bf(v.w) << 16);
    ((uint2*)dst)[i] = make_uint2(lo, hi);
  }
}

// dst[n*dstK + k0 + k] = bf16(src[k*N + n])
__global__ void pack_transpose_k(const float* __restrict__ src,
                                 u16* __restrict__ dst, int K, int N,
                                 int dstK, int k0) {
  int i = blockIdx.x * blockDim.x + threadIdx.x;
  int total = K * N;
  int stride = gridDim.x * blockDim.x;
  for (; i < total; i += stride) {
    int n = i / K, k = i - n * K;
    dst[(size_t)n * dstK + k0 + k] = f2bf(src[(size_t)k * N + n]);
  }
}

// ---------------------------------------------------------------- GEMM
__global__ void __launch_bounds__(256) gemm_kernel(
    const u16* __restrict__ A, const u16* __restrict__ Bt, int N, int K,
    u16* __restrict__ outb, float* __restrict__ outf,
    const float* __restrict__ bias, int mode) {
  const int bn = blockIdx.x * 64;
  const int bm = blockIdx.y * 64;
  const int w = threadIdx.x >> 6;
  const int lane = threadIdx.x & 63;
  const int wm = (w >> 1) * 32, wn = (w & 1) * 32;
  const int fr = lane & 15;
  const int kb = (lane >> 4) * 8;
  v4f acc00 = {0,0,0,0}, acc01 = {0,0,0,0}, acc10 = {0,0,0,0}, acc11 = {0,0,0,0};
  const u16* a0p = A + (size_t)(bm + wm + fr) * K + kb;
  const u16* a1p = a0p + (size_t)16 * K;
  const u16* b0p = Bt + (size_t)(bn + wn + fr) * K + kb;
  const u16* b1p = b0p + (size_t)16 * K;
  for (int kk = 0; kk < K; kk += 32) {
    v8s a0 = *(const v8s*)(a0p + kk);
    v8s a1 = *(const v8s*)(a1p + kk);
    v8s b0 = *(const v8s*)(b0p + kk);
    v8s b1 = *(const v8s*)(b1p + kk);
    acc00 = mfma16(a0, b0, acc00);
    acc01 = mfma16(a0, b1, acc01);
    acc10 = mfma16(a1, b0, acc10);
    acc11 = mfma16(a1, b1, acc11);
  }
  v4f accs[2][2] = {{acc00, acc01}, {acc10, acc11}};
  const int rb = (lane >> 4) * 4;
#pragma unroll
  for (int mi = 0; mi < 2; ++mi)
#pragma unroll
    for (int ni = 0; ni < 2; ++ni)
#pragma unroll
      for (int j = 0; j < 4; ++j) {
        int row = bm + wm + mi * 16 + rb + j;
        int col = bn + wn + ni * 16 + fr;
        float v = accs[mi][ni][j];
        if (mode == 0) {
          int gate = col >> 9, c = col & (H_ - 1);
          outb[(size_t)gate * GS_ + (size_t)row * H_ + c] = f2bf(v);
        } else {
          outf[(size_t)row * N + col] = v + bias[col];
        }
      }
}

// ---------------------------------------------------------------- pipelined
// two-layer GRU scan (r7-proven drain+flag protocol). 192 WGs:
//   bid <  64 : layer-0 role — 4 grp x 16 slabs x 32 cols.
//   bid >= 64 : layer-1 role — 4 grp x 32 slabs x 16 cols, stacked-K
//               [h0(t); h1(t-1)] @ [Win; Wh] (K=1024).
// r9 changes vs r7: (1) L1 seqout/hfinal stores issued AFTER the flagB1
// store (off the drain critical path); (2) loop-end polls moved to loop-top
// and merged into ONE divergent-lane poll loop (flagB0 + flagB1/c1g
// concurrently), overlapped with hoisted xproj loads; (3) h0 broadcast is
// 4-deep parity (backpressure c1g >= t-3: effectively never blocks).
__global__ void __launch_bounds__(256, 1) gru_pipe_kernel(
    const u16* xproj,                // [3][BS_][H_] bf16 (layer-0 z,r,g)
    const u16* __restrict__ Wht0,    // [3][H_][H_]  layer-0 recurrent^T
    const u16* __restrict__ Wstk1,   // [3][H_][1024] layer-1 stacked
    const float* __restrict__ bz0, const float* __restrict__ br0,
    const float* __restrict__ bg0,
    const float* __restrict__ bz1, const float* __restrict__ br1,
    const float* __restrict__ bg1,
    const float* __restrict__ hs,    // [B_][2][H_] f32 initial state
    u16* h0buf,                      // [4][B_][H_] L0 h broadcast (4-parity)
    u16* hr0buf,                     // [B_][H_]    L0 hr exchange
    u16* h1buf,                      // [B_][H_]    L1 h broadcast
    u16* hr1buf,                     // [B_][H_]    L1 hr exchange
    u16* seqout,                     // [B_][S_][H_] layer-1 output (alias z)
    float* __restrict__ hfinal,      // [2*B_][H_] f32 (d_out tail)
    uint32_t* flags) {
  __shared__ __align__(16) char pool[134144];
  const int tid = threadIdx.x;
  const int bid = blockIdx.x;
  const int w = tid >> 6, lane = tid & 63;
  const int fr = lane & 15;
  const int kb = (lane >> 4) * 8;
  const int rb = (lane >> 4) * 4;

  if (bid < 64) {
    // ================= LAYER 0 =================
    u16* ldsW = (u16*)pool;                            // [3][32][HP_]
    u16 (*ldsX)[HP_] = (u16(*)[HP_])(pool + 99840);    // [16][HP_]
    float (*h32)[32] = (float(*)[32])(pool + 116480);  // [16][32]
    const int grp = bid & 3;
    const int slab = bid >> 2;
    const int j0 = slab * 32;
    const int gb = grp * 16;

    for (int idx = tid; idx < 3 * 32 * 64; idx += 256) {
      int gate = idx >> 11;
      int rem = idx & 2047;
      int cl = rem >> 6;
      int kc = (rem & 63) * 8;
      *(v8s*)&ldsW[((gate * 32) + cl) * HP_ + kc] =
          *(const v8s*)(Wht0 + ((size_t)gate * H_ + (j0 + cl)) * H_ + kc);
    }
    for (int i = tid; i < 16 * H_; i += 256) {
      int row = i >> 9, col = i & (H_ - 1);
      ldsX[row][col] = f2bf(hs[((size_t)(gb + row) * 2 + 0) * H_ + col]);
    }
    for (int i = tid; i < 16 * 32; i += 256) {
      int row = i >> 5, cl = i & 31;
      h32[row][cl] = hs[((size_t)(gb + row) * 2 + 0) * H_ + j0 + cl];
    }
    __syncthreads();

    const int nt = w & 1;
    const int gateA = w >> 1;          // waves 0,1 -> z ; waves 2,3 -> r
    const int colL = nt * 16 + fr;
    const int gcol = j0 + colL;
    const float biasA = (gateA == 0) ? bz0[gcol] : br0[gcol];
    const float biasG = bg0[gcol];
    u16* hr0_g = hr0buf + (size_t)gb * H_;
    const u16* xA = xproj + (size_t)gateA * GS_;
    const u16* xG = xproj + (size_t)2 * GS_;
    const u16* wA = ldsW + ((size_t)(gateA * 32) + colL) * HP_;
    const u16* wG = ldsW + ((size_t)(2 * 32) + colL) * HP_;
    uint32_t* flagA0 = flags + (size_t)grp * 16 * FPAD_;
    uint32_t* flagB0 = flags + 1024 + (size_t)grp * 16 * FPAD_;
    uint32_t* c1gg   = flags + 6144 + (size_t)grp * 32 * FPAD_;

    float zv[4] = {0.f, 0.f, 0.f, 0.f};

    for (int t = 0; t < S_; ++t) {
      // hoisted xproj loads (independent of staged data; hide under polls)
      u16 xa_[4], xg_[4];
#pragma unroll
      for (int j = 0; j < 4; ++j) {
        size_t off = ((size_t)(gb + rb + j) * S_ + t) * H_ + gcol;
        xa_[j] = xA[off];
        if (w < 2) xg_[j] = xG[off];
      }

      if (t > 0) {
        // combined concurrent poll (wave 0, divergent-exit):
        // lanes 0-15: flagB0 >= t (all slabs finished phase B(t-1))
        // lanes 16-47: c1g >= t-3 (L1 staged h0(t-4); 4-parity backpressure)
        if (w == 0) {
          const uint32_t* pa = flagB0;
          uint32_t want = 0;
          if (lane < 16) { pa = flagB0 + lane * FPAD_; want = (uint32_t)t; }
          else if (lane < 48) {
            pa = c1gg + (lane - 16) * FPAD_;
            if (t >= 4) want = (uint32_t)(t - 3);
          }
          while (cload32(pa) < want) __builtin_amdgcn_s_sleep(1);
        }
        __syncthreads();
        const uint64_t* src =
            (const uint64_t*)(h0buf + ((size_t)((t - 1) & 3) * B_ + gb) * H_);
        uint64_t vq[8];
#pragma unroll
        for (int i = 0; i < 8; ++i) vq[i] = cload64(src + i * 256 + tid);
#pragma unroll
        for (int i = 0; i < 8; ++i) {
          int d = i * 256 + tid;
          *(uint64_t*)&ldsX[d >> 7][(d & 127) * 4] = vq[i];
        }
        __syncthreads();
      }

      // ---- phase A: z (waves 0,1), r -> hr (waves 2,3) ----
      v4f acc0 = {0,0,0,0}, acc1 = {0,0,0,0};
#pragma unroll
      for (int kk = 0; kk < 8; ++kk) {
        acc0 = mfma16(*(const v8s*)&ldsX[fr][kk * 32 + kb],
                      *(const v8s*)(wA + kk * 32 + kb), acc0);
        acc1 = mfma16(*(const v8s*)&ldsX[fr][256 + kk * 32 + kb],
                      *(const v8s*)(wA + 256 + kk * 32 + kb), acc1);
      }
      float pre[4];
#pragma unroll
      for (int j = 0; j < 4; ++j) {
        float s = acc0[j] + acc1[j] + bf2f(xa_[j]) + biasA;
        pre[j] = 1.0f / (1.0f + __expf(-s));
      }
      if (gateA == 0) {
#pragma unroll
        for (int j = 0; j < 4; ++j) zv[j] = pre[j];
      } else {
#pragma unroll
        for (int j = 0; j < 4; ++j)
          pack_store4(&hr0_g[(size_t)(rb + j) * H_ + gcol],
                      pre[j] * h32[rb + j][colL], fr);
      }
      asm volatile("s_waitcnt vmcnt(0)" ::: "memory");
      slab_barrier<16>(flagA0, slab, (uint32_t)(t + 1), tid);

      {  // stage hr
        const uint64_t* src = (const uint64_t*)hr0_g;
        uint64_t vq[8];
#pragma unroll
        for (int i = 0; i < 8; ++i) vq[i] = cload64(src + i * 256 + tid);
#pragma unroll
        for (int i = 0; i < 8; ++i) {
          int d = i * 256 + tid;
          *(uint64_t*)&ldsX[d >> 7][(d & 127) * 4] = vq[i];
        }
        __syncthreads();
      }

      // ---- phase B: g (waves 0,1), h update + broadcast ----
      if (w < 2) {
        v4f g0 = {0,0,0,0}, g1 = {0,0,0,0};
#pragma unroll
        for (int kk = 0; kk < 8; ++kk) {
          g0 = mfma16(*(const v8s*)&ldsX[fr][kk * 32 + kb],
                      *(const v8s*)(wG + kk * 32 + kb), g0);
          g1 = mfma16(*(const v8s*)&ldsX[fr][256 + kk * 32 + kb],
                      *(const v8s*)(wG + 256 + kk * 32 + kb), g1);
        }
        u16* h0dst = h0buf + ((size_t)(t & 3) * B_ + gb) * H_;
#pragma unroll
        for (int j = 0; j < 4; ++j) {
          int b = gb + rb + j;
          float gval = tanhf(g0[j] + g1[j] + bf2f(xg_[j]) + biasG);
          float hold = h32[rb + j][colL];
          float hnew = zv[j] * hold + (1.0f - zv[j]) * gval;
          h32[rb + j][colL] = hnew;
          pack_store4(&h0dst[(size_t)(rb + j) * H_ + gcol], hnew, fr);
          if (t == S_ - 1) hfinal[(size_t)b * H_ + gcol] = hnew;
        }
      }
      asm volatile("s_waitcnt vmcnt(0)" ::: "memory");
      __syncthreads();
      if (tid == 0)
        cstore32(flagB0 + slab * FPAD_, (uint32_t)(t + 1));
      // poll deferred to next-iteration top (overlaps with prefetch)
    }
  } else {
    // ================= LAYER 1 =================
    u16* ldsW = (u16*)pool;                              // [3][16][KP1_]
    u16 (*ldsX)[KP1_] = (u16(*)[KP1_])(pool + 99072);    // [16][KP1_]
    float (*h32b)[16] = (float(*)[16])(pool + 132096);   // [16][16]
    float (*xg32)[16] = (float(*)[16])(pool + 133120);   // [16][16]
    const int b2 = bid - 64;
    const int grp = b2 & 3;
    const int slab = b2 >> 2;          // 0..31
    const int j0 = slab * 16;
    const int gb = grp * 16;
    const int gcol = j0 + fr;

    for (int idx = tid; idx < 3 * 16 * 128; idx += 256) {
      int gate = idx >> 11;
      int rem = idx & 2047;
      int cl = rem >> 7;
      int kc = (rem & 127) * 8;
      *(v8s*)&ldsW[((gate * 16) + cl) * KP1_ + kc] =
          *(const v8s*)(Wstk1 + ((size_t)(gate * H_) + (j0 + cl)) * 1024 + kc);
    }
    for (int i = tid; i < 16 * H_; i += 256) {
      int row = i >> 9, col = i & (H_ - 1);
      ldsX[row][512 + col] = f2bf(hs[((size_t)(gb + row) * 2 + 1) * H_ + col]);
    }
    for (int i = tid; i < 16 * 16; i += 256) {
      int row = i >> 4, c = i & 15;
      h32b[row][c] = hs[((size_t)(gb + row) * 2 + 1) * H_ + j0 + c];
    }
    __syncthreads();

    const float bzv = bz1[gcol], brv = br1[gcol], bgv = bg1[gcol];
    u16* h1_g = h1buf + (size_t)gb * H_;
    u16* hr1_g = hr1buf + (size_t)gb * H_;
    const u16* wZ = ldsW + ((size_t)(0 * 16) + fr) * KP1_;
    const u16* wR = ldsW + ((size_t)(1 * 16) + fr) * KP1_;
    const u16* wG = ldsW + ((size_t)(2 * 16) + fr) * KP1_;
    uint32_t* flagB0 = flags + 1024 + (size_t)grp * 16 * FPAD_;
    uint32_t* flagA1 = flags + 2048 + (size_t)grp * 32 * FPAD_;
    uint32_t* flagB1 = flags + 4096 + (size_t)grp * 32 * FPAD_;
    uint32_t* c1gg   = flags + 6144 + (size_t)grp * 32 * FPAD_;
    float* hf1 = hfinal + (size_t)B_ * H_;

    float zv[4] = {0.f, 0.f, 0.f, 0.f};

    for (int t = 0; t < S_; ++t) {
      // combined concurrent poll (wave 0, divergent-exit):
      // lanes 0-15: flagB0 >= t+1 (L0's h0(t) ready)
      // lanes 16-47: flagB1 >= t (own h1(t-1) broadcast complete)
      if (w == 0) {
        const uint32_t* pa = flagB0;
        uint32_t want = 0;
        if (lane < 16) { pa = flagB0 + lane * FPAD_; want = (uint32_t)(t + 1); }
        else if (lane < 48) {
          pa = flagB1 + (lane - 16) * FPAD_;
          want = (uint32_t)t;
        }
        while (cload32(pa) < want) __builtin_amdgcn_s_sleep(1);
      }
      __syncthreads();
      {  // stage h0(t) (slot t&3) and h1(t-1)
        const uint64_t* s0 =
            (const uint64_t*)(h0buf + ((size_t)((t & 3)) * B_ + gb) * H_);
        uint64_t q0[8];
#pragma unroll
        for (int i = 0; i < 8; ++i) q0[i] = cload64(s0 + i * 256 + tid);
        if (t > 0) {
          const uint64_t* s1 = (const uint64_t*)h1_g;
          uint64_t q1[8];
#pragma unroll
          for (int i = 0; i < 8; ++i) q1[i] = cload64(s1 + i * 256 + tid);
#pragma unroll
          for (int i = 0; i < 8; ++i) {
            int d = i * 256 + tid;
            *(uint64_t*)&ldsX[d >> 7][512 + (d & 127) * 4] = q1[i];
          }
        }
#pragma unroll
        for (int i = 0; i < 8; ++i) {
          int d = i * 256 + tid;
          *(uint64_t*)&ldsX[d >> 7][(d & 127) * 4] = q0[i];
        }
      }
      __syncthreads();
      if (tid == 0) cstore32(&c1gg[slab * FPAD_], (uint32_t)(t + 1));

      // ---- phase A: w0 z (K=1024), w1 r (K=1024)->hr, w2 xg (K=512) ----
      if (w < 2) {
        const u16* wB = (w == 0) ? wZ : wR;
        v4f a0 = {0,0,0,0}, a1 = {0,0,0,0}, a2 = {0,0,0,0}, a3 = {0,0,0,0};
#pragma unroll
        for (int kk = 0; kk < 8; ++kk) {
          a0 = mfma16(*(const v8s*)&ldsX[fr][kk * 32 + kb],
                      *(const v8s*)(wB + kk * 32 + kb), a0);
          a1 = mfma16(*(const v8s*)&ldsX[fr][256 + kk * 32 + kb],
                      *(const v8s*)(wB + 256 + kk * 32 + kb), a1);
          a2 = mfma16(*(const v8s*)&ldsX[fr][512 + kk * 32 + kb],
                      *(const v8s*)(wB + 512 + kk * 32 + kb), a2);
          a3 = mfma16(*(const v8s*)&ldsX[fr][768 + kk * 32 + kb],
                      *(const v8s*)(wB + 768 + kk * 32 + kb), a3);
        }
        float pre[4];
#pragma unroll
        for (int j = 0; j < 4; ++j) {
          float s = a0[j] + a1[j] + a2[j] + a3[j] + ((w == 0) ? bzv : brv);
          pre[j] = 1.0f / (1.0f + __expf(-s));
        }
        if (w == 0) {
#pragma unroll
          for (int j = 0; j < 4; ++j) zv[j] = pre[j];
        } else {
#pragma unroll
          for (int j = 0; j < 4; ++j)
            pack_store4(&hr1_g[(size_t)(rb + j) * H_ + gcol],
                        pre[j] * h32b[rb + j][fr], fr);
        }
      } else if (w == 2) {
        v4f a0 = {0,0,0,0}, a1 = {0,0,0,0};
#pragma unroll
        for (int kk = 0; kk < 8; ++kk) {
          a0 = mfma16(*(const v8s*)&ldsX[fr][kk * 32 + kb],
                      *(const v8s*)(wG + kk * 32 + kb), a0);
          a1 = mfma16(*(const v8s*)&ldsX[fr][256 + kk * 32 + kb],
                      *(const v8s*)(wG + 256 + kk * 32 + kb), a1);
        }
#pragma unroll
        for (int j = 0; j < 4; ++j) xg32[rb + j][fr] = a0[j] + a1[j];
      }
      asm volatile("s_waitcnt vmcnt(0)" ::: "memory");
      slab_barrier<32>(flagA1, slab, (uint32_t)(t + 1), tid);

      {  // stage hr1 into second half
        const uint64_t* sr = (const uint64_t*)hr1_g;
        uint64_t q[8];
#pragma unroll
        for (int i = 0; i < 8; ++i) q[i] = cload64(sr + i * 256 + tid);
#pragma unroll
        for (int i = 0; i < 8; ++i) {
          int d = i * 256 + tid;
          *(uint64_t*)&ldsX[d >> 7][512 + (d & 127) * 4] = q[i];
        }
        __syncthreads();
      }

      // ---- phase B: w0 g (hr half) + update + broadcast ----
      uint64_t qsv[4];
      float hn[4];
      if (w == 0) {
        v4f g0 = {0,0,0,0}, g1 = {0,0,0,0};
#pragma unroll
        for (int kk = 0; kk < 8; ++kk) {
          g0 = mfma16(*(const v8s*)&ldsX[fr][512 + kk * 32 + kb],
                      *(const v8s*)(wG + 512 + kk * 32 + kb), g0);
          g1 = mfma16(*(const v8s*)&ldsX[fr][768 + kk * 32 + kb],
                      *(const v8s*)(wG + 768 + kk * 32 + kb), g1);
        }
#pragma unroll
        for (int j = 0; j < 4; ++j) {
          float gval = tanhf(g0[j] + g1[j] + xg32[rb + j][fr] + bgv);
          float hold = h32b[rb + j][fr];
          float hnew = zv[j] * hold + (1.0f - zv[j]) * gval;
          h32b[rb + j][fr] = hnew;
          hn[j] = hnew;
          // broadcast h1 (tagged drain below); stash seqout word for later
          float o1 = __shfl_xor(hnew, 1);
          uint32_t c0 = f2bf(hnew), c1 = f2bf(o1);
          uint32_t pk = (fr & 1) ? (c1 | (c0 << 16)) : (c0 | (c1 << 16));
          uint32_t pk2 = __shfl_xor(pk, 2);
          uint64_t qv = (uint64_t)pk | ((uint64_t)pk2 << 32);
          qsv[j] = qv;
          if ((fr & 3) == 0)
            cstore64((uint64_t*)&h1_g[(size_t)(rb + j) * H_ + gcol], qv);
        }
      }
      asm volatile("s_waitcnt vmcnt(0)" ::: "memory");  // drains h1 only
      __syncthreads();
      if (tid == 0) cstore32(flagB1 + slab * FPAD_, (uint32_t)(t + 1));

      // seqout / hfinal: plain stores AFTER the flag (off critical path;
      // acked during the next step's waits)
      if (w == 0) {
#pragma unroll
        for (int j = 0; j < 4; ++j) {
          int b = gb + rb + j;
          if ((fr & 3) == 0)
            *(uint64_t*)&seqout[((size_t)b * S_ + t) * H_ + gcol] = qsv[j];
          if (t == S_ - 1) hf1[(size_t)b * H_ + gcol] = hn[j];
        }
      }
      // flagB1 poll deferred to next-iteration top
    }
  }
}

// ---------------------------------------------------------------- launch
extern "C" void kernel_launch(void* const* d_in, const int* in_sizes, int n_in,
                              void* d_out, int out_size, void* d_ws,
                              size_t ws_size, hipStream_t stream) {
  const float* input = (const float*)d_in[0];
  const float* hs = (const float*)d_in[1];
  const float* W_in[2][3] = {
      {(const float*)d_in[2], (const float*)d_in[5], (const float*)d_in[8]},
      {(const float*)d_in[11], (const float*)d_in[14], (const float*)d_in[17]}};
  const float* W_h[2][3] = {
      {(const float*)d_in[3], (const float*)d_in[6], (const float*)d_in[9]},
      {(const float*)d_in[12], (const float*)d_in[15], (const float*)d_in[18]}};
  const float* bias[2][3] = {
      {(const float*)d_in[4], (const float*)d_in[7], (const float*)d_in[10]},
      {(const float*)d_in[13], (const float*)d_in[16], (const float*)d_in[19]}};
  const float* Wo = (const float*)d_in[20];
  const float* bo = (const float*)d_in[21];
  float* out = (float*)d_out;

  // ---------------- workspace layout (peak ~207.6 MB) ----------------
  char* ws = (char*)d_ws;
  u16* xproj   = (u16*)(ws + 0);             // 201,326,592 B
  u16* wtin0   = (u16*)(ws + 201326592);     // [1536][256]   786,432 B
  u16* wth0    = (u16*)(ws + 202113024);     // [3][512][512] 1,572,864 B
  u16* wstk1   = (u16*)(ws + 203685888);     // [3][512][1024] 3,145,728 B
  u16* wot     = (u16*)(ws + 206831616);     // [256][512]    262,144 B
  u16* h0buf   = (u16*)(ws + 207093760);     // [4][64][512]  262,144 B
  u16* hr0buf  = (u16*)(ws + 207355904);     // [64][512]      65,536 B
  u16* h1buf   = (u16*)(ws + 207421440);     // [64][512]      65,536 B
  u16* hr1buf  = (u16*)(ws + 207486976);     // [64][512]      65,536 B
  uint32_t* flags = (uint32_t*)(ws + 207552512); // 8192 u32 = 32,768 B

  u16* inbf = (u16*)d_out;                   // 33.5 MB in d_out y-region
  u16* seq2 = xproj;                         // layer-1 seq aliases z-slice

  // 1. cast input to bf16 (into d_out y-region scratch)
  cast_input_kernel<<<2048, 256, 0, stream>>>(input, inbf, BS_ * IN_ / 4);

  // 2. pack weights: L0 separate, L1 stacked [Win; Wh] (K=1024)
  for (int g = 0; g < 3; ++g) {
    pack_transpose_k<<<256, 256, 0, stream>>>(
        W_in[0][g], wtin0 + (size_t)g * H_ * IN_, IN_, H_, IN_, 0);
    pack_transpose_k<<<256, 256, 0, stream>>>(
        W_h[0][g], wth0 + (size_t)g * H_ * H_, H_, H_, H_, 0);
    pack_transpose_k<<<256, 256, 0, stream>>>(
        W_in[1][g], wstk1 + (size_t)g * H_ * 1024, H_, H_, 1024, 0);
    pack_transpose_k<<<256, 256, 0, stream>>>(
        W_h[1][g], wstk1 + (size_t)g * H_ * 1024, H_, H_, 1024, 512);
  }
  pack_transpose_k<<<256, 256, 0, stream>>>(Wo, wot, H_, OUT_, H_, 0);

  // 3. layer-0 input projections for all timesteps: [BS] x [1536]
  gemm_kernel<<<dim3(24, 1024), 256, 0, stream>>>(
      inbf, wtin0, 1536, IN_, xproj, nullptr, nullptr, 0);

  // 4. zero flags (replay safety), run the pipelined scan (192 WGs)
  hipMemsetAsync(flags, 0, 32768, stream);
  const size_t ysz = (size_t)BS_ * OUT_;
  float* hfin = out + ysz;
  gru_pipe_kernel<<<dim3(192), dim3(256), 0, stream>>>(
      xproj, wth0, wstk1, bias[0][0], bias[0][1], bias[0][2], bias[1][0],
      bias[1][1], bias[1][2], hs, h0buf, hr0buf, h1buf, hr1buf, seq2, hfin,
      flags);

  // 5. output projection: y = seq2 @ Wo + bo (overwrites inbf, dead by now)
  gemm_kernel<<<dim3(4, 1024), 256, 0, stream>>>(seq2, wot, OUT_, H_, nullptr,
                                                 out, bo, 1);
}